// Round 2
// baseline (15136.140 us; speedup 1.0000x reference)
//
#include <hip/hip_runtime.h>
#include <stdint.h>

// DMLSTM on MI355X.
// Phase 0: transpose W fp32[1024][2560] -> Wt f16[2560][1024] (n-major, k contiguous)
// Phase 1: Zx = X @ Wx + b  (big f16-MFMA GEMM, parallel, stored f16 in ws)
// Phase 2: persistent recurrent kernel: 4 batch-groups x 32 blocks (1 per CU, 128 CUs);
//          each block owns 16 h-cols (80 z-cols); W_h slice (80KB) in LDS.
//          Per-step sync via SELF-TAGGED payload words (tag16|h16) in LIC,
//          double-buffered by step parity. 32 blocks/group halves the redundant
//          LIC all-gather traffic vs 64 (contention was inflating RTT).

typedef _Float16 h8 __attribute__((ext_vector_type(8)));
typedef _Float16 h4v __attribute__((ext_vector_type(4)));
typedef float f4 __attribute__((ext_vector_type(4)));

#define SCOPE_AGENT __HIP_MEMORY_SCOPE_AGENT

__device__ __forceinline__ float sigf(float x) {
  x = fminf(fmaxf(x, -40.f), 40.f);
  return 1.f / (1.f + __expf(-x));
}
__device__ __forceinline__ float tanh_f(float x) {
  x = fminf(fmaxf(x, -20.f), 20.f);
  const float e = __expf(2.f * x);
  return (e - 1.f) / (e + 1.f);
}

// ---------------- Phase 0: W -> Wt (f16, transposed) ----------------
__global__ __launch_bounds__(256) void k_wt(const float* __restrict__ W,
                                            _Float16* __restrict__ Wt) {
  __shared__ __align__(16) _Float16 tl[64][68];
  const int bk = blockIdx.x & 15;   // 1024/64 = 16 tiles in k
  const int bn = blockIdx.x >> 4;   // 2560/64 = 40 tiles in n
  const int t = threadIdx.x;
  {
    const int r = t >> 2, c4 = t & 3;
    const float4* s4 = (const float4*)(W + (size_t)(bk * 64 + r) * 2560 + bn * 64 + c4 * 16);
#pragma unroll
    for (int i = 0; i < 4; i++) {
      float4 v = s4[i];
      tl[r][c4 * 16 + i * 4 + 0] = (_Float16)v.x;
      tl[r][c4 * 16 + i * 4 + 1] = (_Float16)v.y;
      tl[r][c4 * 16 + i * 4 + 2] = (_Float16)v.z;
      tl[r][c4 * 16 + i * 4 + 3] = (_Float16)v.w;
    }
  }
  __syncthreads();
  {
    const int nr = t >> 2, kk = (t & 3) * 16;
    h8 o0, o1;
#pragma unroll
    for (int i = 0; i < 8; i++) {
      o0[i] = tl[kk + i][nr];
      o1[i] = tl[kk + 8 + i][nr];
    }
    _Float16* dst = Wt + (size_t)(bn * 64 + nr) * 1024 + bk * 64 + kk;
    *(h8*)dst = o0;
    *(h8*)(dst + 8) = o1;
  }
}

// ---------------- Phase 1: Zx = X @ Wx + b ----------------
__global__ __launch_bounds__(256) void k_zx(const float* __restrict__ X,
                                            const _Float16* __restrict__ Wt,
                                            const float* __restrict__ bias,
                                            _Float16* __restrict__ Zx,
                                            int s_base, int CS) {
  __shared__ __align__(16) _Float16 As[128][72];
  __shared__ __align__(16) _Float16 Bs[128][72];
  const int bid = blockIdx.x;
  const int nblk = bid % 20;        // 2560/128
  const int mblk = bid / 20;        // n-inner ordering -> concurrent blocks share X stripe
  const int tilesPerB = CS >> 7;
  const int b = mblk / tilesPerB;
  const int s0 = (mblk - b * tilesPerB) << 7;
  const int t = threadIdx.x;
  const int wid = t >> 6, lane = t & 63;
  const int wr = wid >> 1, wc = wid & 1;
  const int lr = (lane >> 4) * 4, lc = lane & 15;
  const int koff = (lane >> 4) * 8;

  const f4 zero4 = {0.f, 0.f, 0.f, 0.f};
  f4 acc[4][4];
#pragma unroll
  for (int i = 0; i < 4; i++)
#pragma unroll
    for (int j = 0; j < 4; j++) acc[i][j] = zero4;

  const float* Xb = X + ((size_t)b * 2048 + (size_t)(s_base + s0)) * 512;
  const _Float16* Bb = Wt + (size_t)nblk * 128 * 1024;
  const int rA = t >> 1, hf = t & 1;

  for (int k0 = 0; k0 < 512; k0 += 64) {
    const float4* s4 = (const float4*)(Xb + (size_t)rA * 512 + k0 + hf * 32);
#pragma unroll
    for (int i = 0; i < 8; i++) {
      float4 v = s4[i];
      h4v o = {(_Float16)v.x, (_Float16)v.y, (_Float16)v.z, (_Float16)v.w};
      *(h4v*)&As[rA][hf * 32 + i * 4] = o;
    }
    const h8* bs = (const h8*)(Bb + (size_t)rA * 1024 + k0 + hf * 32);
#pragma unroll
    for (int i = 0; i < 4; i++) *(h8*)&Bs[rA][hf * 32 + i * 8] = bs[i];
    __syncthreads();
#pragma unroll
    for (int kk = 0; kk < 2; kk++) {
      h8 af[4], bf[4];
      const int kr = kk * 32 + koff;
#pragma unroll
      for (int i = 0; i < 4; i++) af[i] = *(const h8*)&As[wr * 64 + i * 16 + lc][kr];
#pragma unroll
      for (int j = 0; j < 4; j++) bf[j] = *(const h8*)&Bs[wc * 64 + j * 16 + lc][kr];
#pragma unroll
      for (int i = 0; i < 4; i++)
#pragma unroll
        for (int j = 0; j < 4; j++)
          acc[i][j] = __builtin_amdgcn_mfma_f32_16x16x32_f16(af[i], bf[j], acc[i][j], 0, 0, 0);
    }
    __syncthreads();
  }
#pragma unroll
  for (int j = 0; j < 4; j++) {
    const int col = nblk * 128 + wc * 64 + j * 16 + lc;
    const float bc = bias[col];
#pragma unroll
    for (int i = 0; i < 4; i++) {
#pragma unroll
      for (int r = 0; r < 4; r++) {
        const int srow = s0 + wr * 64 + i * 16 + lr + r;
        Zx[((size_t)b * CS + srow) * 2560 + col] = (_Float16)(acc[i][j][r] + bc);
      }
    }
  }
}

// ---------------- Phase 2: persistent recurrence ----------------
// grid = 128 blocks x 256 thr. grp = bid>>5 owns batches [grp*16, grp*16+16).
// ci (0..31) XCD-swizzled: blocks on the same XCD own adjacent 64-col spans.
// Block owns h-cols [ci*16, ci*16+16) -> z-cols {g*512 + ci*16 + j : g<5, j<16}.
// hbuf word = (tag16 << 16) | h_f16_bits ; tag = global_step + 1 ; 2 buffers by parity.
__global__ __launch_bounds__(256) void k_rec(
    const _Float16* __restrict__ Zx, const _Float16* __restrict__ Wt,
    float* __restrict__ Y, uint32_t* __restrict__ hbuf,
    _Float16* __restrict__ hstate, float* __restrict__ cstate,
    int s_base, int CS) {
  __shared__ __align__(16) _Float16 WsT[80][520];  // [local z-col][k] (k of h-part), 83.2KB
  __shared__ __align__(16) _Float16 hs[16][520];   // staged h(t) f16
  __shared__ __align__(16) float zsh[16][84];      // z slice fp32 (zx folded in)
  __shared__ __align__(16) _Float16 zxs[16][80];   // Zx slice for step t
  __shared__ __align__(16) float cbuf[256];        // c state [m][j]

  const int bid = blockIdx.x;
  const int grp = bid >> 5;                              // 4 groups of 32 blocks
  const int ci = ((bid & 7) << 2) | ((bid >> 3) & 3);    // XCD-contiguous column owner
  const int tid = threadIdx.x;
  const int wid = tid >> 6, lane = tid & 63;
  const int hbase = ci * 16;

  // load W_h slice once: WsT[g*16+jc][k] = Wt[g*512+hbase+jc][512+k]  (80 rows x 1KB)
#pragma unroll
  for (int i = 0; i < 20; i++) {
    const int idx = i * 256 + tid;
    const int lcw = idx >> 6;   // 0..79
    const int ch = idx & 63;    // 8-f16 chunk
    const int g = lcw >> 4, jc = lcw & 15;
    const h8* src = (const h8*)(Wt + (size_t)(g * 512 + hbase + jc) * 1024 + 512 + ch * 8);
    *(h8*)&WsT[lcw][ch * 8] = *src;
  }
  cbuf[tid] = cstate[((size_t)(grp * 32 + ci)) * 256 + tid];
  if (tid < 128) {
    // publish h(s_base) tagged into buffer (s_base & 1): 16 cols as 8 u64 pairs per m
    const int m = tid >> 3, jj = (tid & 7) * 2;
    uint32_t hv2;
    __builtin_memcpy(&hv2, hstate + (size_t)(grp * 16 + m) * 512 + hbase + jj, 4);
    const uint32_t tg = (uint32_t)(s_base + 1) << 16;
    const uint64_t v = ((uint64_t)(tg | (hv2 >> 16)) << 32) | (tg | (hv2 & 0xffffu));
    __hip_atomic_store(
        (uint64_t*)&hbuf[((size_t)((s_base & 1) * 4 + grp) * 16 + m) * 512 + hbase + jj],
        v, __ATOMIC_RELAXED, SCOPE_AGENT);
  }
  __syncthreads();

  uint32_t* hs32 = (uint32_t*)&hs[0][0];

  for (int t = 0; t < CS; t++) {
    const int G = s_base + t;
    const uint32_t tag = (uint32_t)(G + 1);
    // issue Zx prefetch into regs (threads 0..159; 16 rows x 10 h8-chunks),
    // consumed into LDS after the spin -> HBM latency hides under tag-detect
    h8 zxr;
    const int zm = tid / 10, zc8 = tid % 10;
    if (tid < 160) {
      zxr = *(const h8*)(Zx + ((size_t)(grp * 16 + zm) * CS + t) * 2560 +
                         (zc8 >> 1) * 512 + hbase + (zc8 & 1) * 8);
    }
    // stage h(t): all 256 threads read tagged u64 pairs, spin-on-data, write LDS
    {
      const uint64_t* src =
          (const uint64_t*)(hbuf + (size_t)((G & 1) * 4 + grp) * 16 * 512);
      uint64_t w[16];
#pragma unroll
      for (int i = 0; i < 16; i++)
        w[i] = __hip_atomic_load(&src[i * 256 + tid], __ATOMIC_RELAXED, SCOPE_AGENT);
#pragma unroll
      for (int i = 0; i < 16; i++) {
        while ((((uint32_t)w[i] >> 16) != tag) |
               (((uint32_t)(w[i] >> 48)) != tag))
          w[i] = __hip_atomic_load(&src[i * 256 + tid], __ATOMIC_RELAXED, SCOPE_AGENT);
        hs32[i * 260 + tid] =
            ((uint32_t)w[i] & 0xffffu) | (((uint32_t)(w[i] >> 32) & 0xffffu) << 16);
      }
    }
    if (tid < 160) *(h8*)&zxs[zm][zc8 * 8] = zxr;
    __syncthreads();
    // z = h @ Wh + Zx: 5 tiles of 16 cols; wave w -> tile w, wave 0 also tile 4.
    {
      const int cloc = lane & 15;
      const int koffv = (lane >> 4) * 8;
      const int rb = (lane >> 4) * 4;
#pragma unroll
      for (int rep = 0; rep < 2; rep++) {
        if (rep == 0 || wid == 0) {
          const int tl = (rep == 0) ? wid : 4;
          f4 acc = {0.f, 0.f, 0.f, 0.f};
#pragma unroll
          for (int ks = 0; ks < 16; ks++) {
            const h8 a = *(const h8*)&hs[cloc][ks * 32 + koffv];
            const h8 b = *(const h8*)&WsT[tl * 16 + cloc][ks * 32 + koffv];
            acc = __builtin_amdgcn_mfma_f32_16x16x32_f16(a, b, acc, 0, 0, 0);
          }
#pragma unroll
          for (int r = 0; r < 4; r++)
            zsh[rb + r][tl * 16 + cloc] = acc[r] + (float)zxs[rb + r][tl * 16 + cloc];
        }
      }
    }
    __syncthreads();
    // gates + state update + DIRECT tagged publish (packed u64, 2 cols/thread)
    if (tid < 128) {
      const int m = tid >> 3, jj = (tid & 7) * 2;
      float hv[2], cn2[2];
#pragma unroll
      for (int u = 0; u < 2; u++) {
        const int j = jj + u;
        const float zi = zsh[m][j];
        const float zf = zsh[m][16 + j];
        const float zo = zsh[m][32 + j];
        const float zc = zsh[m][48 + j];
        const float zd = zsh[m][64 + j];
        const float ig = sigf(zi), fg = sigf(zf), og = sigf(zo);
        const float c0 = cbuf[m * 16 + j];
        const float cp = fg * c0 + ig * tanh_f(zc);
        const float dg = tanh_f(zd);
        const float cn = cp + dg * (cp - c0);
        hv[u] = og * tanh_f(cn);
        cn2[u] = cn;
        cbuf[m * 16 + j] = cn;
      }
      _Float16 h0 = (_Float16)hv[0], h1 = (_Float16)hv[1];
      uint16_t b0, b1;
      __builtin_memcpy(&b0, &h0, 2);
      __builtin_memcpy(&b1, &h1, 2);
      const uint32_t tg = (uint32_t)(G + 2) << 16;
      const uint64_t v = ((uint64_t)(tg | b1) << 32) | (tg | b0);
      __hip_atomic_store(
          (uint64_t*)&hbuf[((size_t)(((G + 1) & 1) * 4 + grp) * 16 + m) * 512 + hbase + jj],
          v, __ATOMIC_RELAXED, SCOPE_AGENT);
      asm volatile("" ::: "memory");  // keep publish ahead of Y store
      float2 yv;
      yv.x = hv[0];
      yv.y = hv[1];
      *(float2*)&Y[((size_t)(grp * 16 + m) * 2048 + (size_t)G) * 512 + hbase + jj] = yv;
      if (t == CS - 1) {
        cstate[((size_t)(grp * 32 + ci)) * 256 + m * 16 + jj] = cn2[0];
        cstate[((size_t)(grp * 32 + ci)) * 256 + m * 16 + jj + 1] = cn2[1];
        const uint32_t hh = ((uint32_t)b1 << 16) | b0;
        __builtin_memcpy(hstate + (size_t)(grp * 16 + m) * 512 + hbase + jj, &hh, 4);
      }
    }
  }
}

extern "C" void kernel_launch(void* const* d_in, const int* in_sizes, int n_in,
                              void* d_out, int out_size, void* d_ws, size_t ws_size,
                              hipStream_t stream) {
  const float* X = (const float*)d_in[0];
  const float* W = (const float*)d_in[1];
  const float* bias = (const float*)d_in[2];
  float* Y = (float*)d_out;
  char* ws = (char*)d_ws;

  const size_t szWt = (size_t)2560 * 1024 * 2;  // 5.24 MB
  // choose largest S-chunk whose Zx ring fits in ws (slack covers hbuf/hstate/cstate)
  int CS = 128;
  for (int c = 2048; c >= 128; c >>= 1) {
    const size_t need = szWt + (size_t)64 * c * 2560 * 2 + 512 * 1024;
    if (need <= ws_size) { CS = c; break; }
  }
  const size_t offZx = szWt;
  const size_t szZx = (size_t)64 * CS * 2560 * 2;
  const size_t offHbuf = offZx + szZx;
  const size_t szHbuf = (size_t)2 * 4 * 16 * 512 * 4;  // 262144 (tagged, dbuf)
  const size_t offHst = offHbuf + szHbuf;
  const size_t szHst = (size_t)4 * 16 * 512 * 2;       // 65536
  const size_t offCst = offHst + szHst;
  const size_t szCst = (size_t)4 * 32 * 256 * 4;       // 131072

  _Float16* Wt = (_Float16*)(ws + 0);
  _Float16* Zx = (_Float16*)(ws + offZx);
  uint32_t* hbuf = (uint32_t*)(ws + offHbuf);
  _Float16* hstate = (_Float16*)(ws + offHst);
  float* cstate = (float*)(ws + offCst);

  k_wt<<<640, 256, 0, stream>>>(W, Wt);
  // zero tags + h(0) + c(0) once per launch (tag 0 never matches any expected tag >= 1)
  (void)hipMemsetAsync(ws + offHbuf, 0, szHbuf + szHst + szCst, stream);

  const int nch = 2048 / CS;
  for (int ch = 0; ch < nch; ch++) {
    const int sb = ch * CS;
    k_zx<<<CS * 10, 256, 0, stream>>>(X, Wt, bias, Zx, sb, CS);
    k_rec<<<128, 256, 0, stream>>>(Zx, Wt, Y, hbuf, hstate, cstate, sb, CS);
  }
  (void)in_sizes; (void)n_in; (void)out_size;
}